// Round 15
// baseline (127.207 us; speedup 1.0000x reference)
//
#include <hip/hip_runtime.h>
#include <hip/hip_bf16.h>

#define B_    16
#define N_    4
#define COUT  256
#define CIN   256
#define H_    64
#define W_    64
#define K_TOT (CIN * 9)    // 2304, k = p*256 + cin (p-major)
#define HW    (H_ * W_)    // 4096
#define NKT   72           // K-tiles of 32
#define PAD   66
#define PLANE (PAD * PAD)  // 4356 padded pixels per (b, cb4) plane

typedef __attribute__((ext_vector_type(8))) short short8;
typedef __attribute__((ext_vector_type(4))) float f32x4;
typedef unsigned short ushort_t;

static __device__ __forceinline__ ushort_t f2bf(float f) {
    __hip_bfloat16 h = __float2bfloat16(f);
    return *reinterpret_cast<ushort_t*>(&h);
}

typedef __attribute__((address_space(3))) unsigned int lds_u32;
typedef __attribute__((address_space(1))) const unsigned int glb_u32;
static __device__ __forceinline__ void gl_lds16(const ushort_t* g, ushort_t* l) {
    __builtin_amdgcn_global_load_lds((glb_u32*)g, (lds_u32*)l, 16, 0, 0);
}

#define BARRIER() asm volatile("s_barrier" ::: "memory")
#define VMCNTN(N) asm volatile("s_waitcnt vmcnt(" #N ")" ::: "memory")

// ---------------------------------------------------------------------------
// Kernel 1 (fused rot + build_rw): rw[b][cout][p*256 + cin] (bf16, p-major).
// grid 256 blocks x 256 thr; weight read ONCE (loop over b inside).
// Threads 0..63 recompute the 64 alpha-scaled 9x9 rotation matrices in smem.
// ---------------------------------------------------------------------------
__global__ __launch_bounds__(256)
void build_rw_kernel(const float* __restrict__ weight,
                     const float* __restrict__ alphas,
                     const float* __restrict__ angles,
                     ushort_t* __restrict__ rw) {
    __shared__ float rms[B_ * N_ * 81];   // 5184 floats = 20.7 KB
    int tid = threadIdx.x;

    if (tid < B_ * N_) {
        float th = angles[tid], al = alphas[tid];
        float xc = cosf(th), ys = sinf(th);
        float a = xc - ys, b = xc * ys, c = xc + ys;
        float r[81];
#pragma unroll
        for (int j = 0; j < 81; ++j) r[j] = 0.f;
        if (th >= 0.f) {
            r[0] = a;          r[1] = 1.f - a;
            r[10] = xc - b;    r[11] = b;        r[13] = 1.f - c + b; r[14] = ys - b;
            r[20] = a;         r[23] = 1.f - a;
            r[27] = b;         r[28] = ys - b;   r[30] = xc - b;      r[31] = 1.f - c + b;
            r[40] = 1.f;
            r[49] = 1.f - c + b; r[50] = xc - b; r[52] = ys - b;      r[53] = b;
            r[57] = 1.f - a;   r[60] = a;
            r[66] = ys - b;    r[67] = 1.f - c + b; r[69] = b;        r[70] = xc - b;
            r[79] = 1.f - a;   r[80] = a;
        } else {
            r[0] = c;          r[3] = 1.f - c;
            r[9] = -b;         r[10] = xc + b;   r[12] = b - ys;      r[13] = 1.f - a - b;
            r[19] = 1.f - c;   r[20] = c;
            r[30] = xc + b;    r[31] = 1.f - a - b; r[33] = -b;       r[34] = b - ys;
            r[40] = 1.f;
            r[46] = b - ys;    r[47] = -b;       r[49] = 1.f - a - b; r[50] = xc + b;
            r[60] = c;         r[61] = 1.f - c;
            r[67] = 1.f - a - b; r[68] = b - ys; r[70] = xc + b;      r[71] = -b;
            r[77] = 1.f - c;   r[80] = c;
        }
#pragma unroll
        for (int j = 0; j < 81; ++j) rms[tid * 81 + j] = r[j] * al;
    }
    __syncthreads();

    int idx = blockIdx.x * 256 + tid;     // cout*256 + cin
    int cout = idx >> 8, cin = idx & 255;

    float wv[N_][9];
#pragma unroll
    for (int n = 0; n < N_; ++n)
#pragma unroll
        for (int q = 0; q < 9; ++q)
            wv[n][q] = weight[(size_t)(n * (COUT * CIN) + idx) * 9 + q];

    for (int b = 0; b < B_; ++b) {
        const float* rmb = &rms[b * N_ * 81];
        ushort_t* dst = rw + (size_t)(b * COUT + cout) * K_TOT + cin;
#pragma unroll
        for (int p = 0; p < 9; ++p) {
            float s = 0.f;
#pragma unroll
            for (int n = 0; n < N_; ++n)
#pragma unroll
                for (int q = 0; q < 9; ++q)
                    s += rmb[n * 81 + p * 9 + q] * wv[n][q];
            dst[p * 256] = f2bf(s);
        }
    }
}

// ---------------------------------------------------------------------------
// Kernel 2 (fused nhwc repack + halo zero): x fp32 [b][c][64][64] -> xt bf16
//   [b][cb4(4)][y+1][x+1][64cin], plus zeroed halo ring.
// grid (64 rows, 8 cb32, B_), 256 thr.
// ---------------------------------------------------------------------------
__global__ __launch_bounds__(256)
void nhwc_kernel(const float* __restrict__ x, ushort_t* __restrict__ xt) {
    int y    = blockIdx.x;
    int cb32 = blockIdx.y;
    int b    = blockIdx.z;
    __shared__ ushort_t tileT[64][40];    // [px][ci(32)], 80B rows
    int t = threadIdx.x;

    ushort_t* plane = xt + (size_t)(b * 4 + (cb32 >> 1)) * PLANE * 64 + (cb32 & 1) * 32;
    const int4 z = {0, 0, 0, 0};

    int ci = t & 31, seg = t >> 5;        // 8 segs x 8 px
    const float* src = x + ((size_t)(b * CIN + cb32 * 32 + ci) * HW + y * 64 + seg * 8);
    float4 f0 = ((const float4*)src)[0];
    float4 f1 = ((const float4*)src)[1];
#pragma unroll
    for (int q = 0; q < 4; ++q) tileT[seg * 8 + q][ci]     = f2bf(((float*)&f0)[q]);
#pragma unroll
    for (int q = 0; q < 4; ++q) tileT[seg * 8 + 4 + q][ci] = f2bf(((float*)&f1)[q]);

    // ---- halo: left/right pad of this row (r = y+1), this 32-cin half ----
    if (t < 8) {
        int col = (t >> 2) ? 65 : 0;
        int sg  = t & 3;
        *(int4*)(plane + ((size_t)(y + 1) * PAD + col) * 64 + sg * 8) = z;
    }
    // ---- halo: top/bottom rows (y==0 blocks only) ----
    if (y == 0) {
        for (int u = t; u < 528; u += 256) {
            int row = (u >= 264) ? 65 : 0;
            int v = (u >= 264) ? u - 264 : u;   // 0..263
            int px = v >> 2, sg = v & 3;
            *(int4*)(plane + ((size_t)row * PAD + px) * 64 + sg * 8) = z;
        }
    }
    __syncthreads();

    int px = t >> 2, cseg = t & 3;        // 64 px x 4 x 16B
    ushort_t* dst = plane + ((size_t)(y + 1) * PAD + px + 1) * 64 + cseg * 8;
    *(int4*)dst = *(const int4*)&tileT[px][cseg * 8];
}

// ---------------------------------------------------------------------------
// Kernel 3: 256x256 implicit-GEMM conv (byte-identical to R14 best, 90-91us).
// BK=32, ring-3 LDS + cross-tile register fragment prefetch; pair-row 128B
// LDS rows + involution swizzle (0-conflict), setprio, XCD swizzle.
// 512 thr = 8 waves (2Mx4N), wave 128x64, acc[8][4].
// ---------------------------------------------------------------------------
__global__ __launch_bounds__(512, 1)
void conv_kernel(const ushort_t* __restrict__ xt,
                 const ushort_t* __restrict__ rw,
                 float* __restrict__ out) {
    int bid0 = blockIdx.x;
    int bid = (bid0 & 7) * 32 + (bid0 >> 3);   // 256 = 8*32: bijective
    int b     = bid >> 4;
    int ptile = bid & 15;       // pixel tile: 4 image rows
    int y0 = ptile * 4;
    int tid = threadIdx.x;
    int lane = tid & 63, wid = tid >> 6;
    int wm = wid >> 2, wn = wid & 3;
    int rA = lane & 15, kseg = lane >> 4;

    __shared__ __align__(16) ushort_t As[3][8192];   // 3 x 16 KB (256 rows x 32k)
    __shared__ __align__(16) ushort_t Bs[3][8192];   // 3 x 16 KB (256 px x 32k)
    ushort_t* AsB = &As[0][0];
    ushort_t* BsB = &Bs[0][0];

    f32x4 acc[8][4] = {};

    const ushort_t* rwb = rw + (size_t)b * COUT * K_TOT;
    const ushort_t* xtb = xt + ((size_t)b * 4 * PLANE + (size_t)y0 * PAD) * 64;

    // ---- staging geometry (pair-row packing, R12-proven) ----
    int asrc[2], bsrc[2], uDst[2];
#pragma unroll
    for (int i = 0; i < 2; ++i) {
        int u = i * 512 + tid;
        int l = u >> 3, s = u & 7;
        int c = s ^ (l & 7);
        int row = 2 * l + (c >> 2);                // 0..255
        asrc[i] = row * K_TOT + (c & 3) * 8;
        bsrc[i] = ((row >> 6) * PAD + (row & 63)) * 64 + (c & 3) * 8;
        uDst[i] = u * 8;
    }
    // ---- read geometry (lane-constant slot, R12-proven) ----
    const int slotR = (kseg + 4 * (rA & 1)) ^ ((rA >> 1) & 7);
    const int aRd = (wm * 64 + (rA >> 1)) * 64 + slotR * 8;   // + mi*512
    const int bRd = (wn * 32 + (rA >> 1)) * 64 + slotR * 8;   // + ni*512

#define STAGE_AB(KT, Q)                                                        \
    {                                                                          \
        int p_ = (KT) >> 3, sub_ = (KT) & 7;                                   \
        int ako = p_ * 256 + sub_ * 32;                                        \
        gl_lds16(rwb + asrc[0] + ako, AsB + (Q) * 8192 + uDst[0]);             \
        gl_lds16(rwb + asrc[1] + ako, AsB + (Q) * 8192 + uDst[1]);             \
        int ph_ = p_ / 3, pw_ = p_ - 3 * ph_;                                  \
        const ushort_t* sb_ = xtb + (size_t)((sub_ >> 1) * PLANE + ph_ * PAD + pw_) * 64 \
                              + (sub_ & 1) * 32;                               \
        gl_lds16(sb_ + bsrc[0], BsB + (Q) * 8192 + uDst[0]);                   \
        gl_lds16(sb_ + bsrc[1], BsB + (Q) * 8192 + uDst[1]);                   \
    }

#define READ_FRAGS(Q, AF, BF)                                                  \
    _Pragma("unroll")                                                          \
    for (int mi = 0; mi < 8; ++mi)                                             \
        AF[mi] = *(const short8*)(AsB + (Q) * 8192 + aRd + mi * 512);          \
    _Pragma("unroll")                                                          \
    for (int ni = 0; ni < 4; ++ni)                                             \
        BF[ni] = *(const short8*)(BsB + (Q) * 8192 + bRd + ni * 512);

    // body: prefetch frags(kt+1) into (AFN,BFN); stage kt+2; MFMA on (AFC,BFC)
#define TILE_BODY(KT, QN, QS, AFC, BFC, AFN, BFN)                              \
    {                                                                          \
        if ((KT) + 1 < NKT) { READ_FRAGS(QN, AFN, BFN); }                      \
        if ((KT) + 2 < NKT) { STAGE_AB((KT) + 2, QS); }                        \
        __builtin_amdgcn_s_setprio(1);                                         \
        _Pragma("unroll")                                                      \
        for (int mi = 0; mi < 8; ++mi)                                         \
            _Pragma("unroll")                                                  \
            for (int ni = 0; ni < 4; ++ni)                                     \
                acc[mi][ni] = __builtin_amdgcn_mfma_f32_16x16x32_bf16(         \
                    AFC[mi], BFC[ni], acc[mi][ni], 0, 0, 0);                   \
        __builtin_amdgcn_s_setprio(0);                                         \
        VMCNTN(0);                                                             \
        BARRIER();                                                             \
    }

    // ---- prologue: stage tiles 0,1 into buffers 0,1; prefetch frags(0) ----
    STAGE_AB(0, 0);
    STAGE_AB(1, 1);
    VMCNTN(0);
    BARRIER();

    short8 afA[8], bfA[4], afB[8], bfB[4];
    READ_FRAGS(0, afA, bfA);

    int qc = 0;                      // buffer of current tile
    for (int kt = 0; kt < NKT; kt += 2) {
        int qn = qc + 1; if (qn >= 3) qn -= 3;
        int qs = qc + 2; if (qs >= 3) qs -= 3;
        TILE_BODY(kt, qn, qs, afA, bfA, afB, bfB);
        // second tile of pair: current buffer qn
        int qn2 = qs;
        int qs2 = qc;
        TILE_BODY(kt + 1, qn2, qs2, afB, bfB, afA, bfA);
        qc = qs;                     // (qc+2)%3 after two tiles
    }
#undef TILE_BODY
#undef READ_FRAGS
#undef STAGE_AB

    // ---- epilogue: D[row=(lane>>4)*4+rr][col=lane&15] ----
    int row0 = (lane >> 4) * 4;
    int col  = lane & 15;
    float* outb = out + (size_t)b * COUT * HW + ptile * 256;
#pragma unroll
    for (int am = 0; am < 8; ++am)
#pragma unroll
        for (int an = 0; an < 4; ++an)
#pragma unroll
            for (int rr = 0; rr < 4; ++rr) {
                int m = wm * 128 + am * 16 + row0 + rr;
                int n = wn * 64 + an * 16 + col;
                outb[(size_t)m * HW + n] = acc[am][an][rr];
            }
}

// ---------------------------------------------------------------------------
extern "C" void kernel_launch(void* const* d_in, const int* in_sizes, int n_in,
                              void* d_out, int out_size, void* d_ws, size_t ws_size,
                              hipStream_t stream) {
    const float* x      = (const float*)d_in[0];
    const float* alphas = (const float*)d_in[1];
    const float* angles = (const float*)d_in[2];
    const float* weight = (const float*)d_in[3];
    float* out = (float*)d_out;

    // ws: rw 18.87 MB | xt 35.68 MB
    ushort_t* rw = (ushort_t*)d_ws;
    ushort_t* xt = (ushort_t*)((char*)d_ws + (size_t)B_ * COUT * K_TOT * 2);

    build_rw_kernel<<<COUT * CIN / 256, 256, 0, stream>>>(weight, alphas, angles, rw);
    nhwc_kernel<<<dim3(64, 8, B_), 256, 0, stream>>>(x, xt);
    conv_kernel<<<256, 512, 0, stream>>>(xt, rw, out);
}

// Round 16
// 111.527 us; speedup vs baseline: 1.1406x; 1.1406x over previous
//
#include <hip/hip_runtime.h>
#include <hip/hip_bf16.h>

#define B_    16
#define N_    4
#define COUT  256
#define CIN   256
#define H_    64
#define W_    64
#define K_TOT (CIN * 9)    // 2304, k = p*256 + cin (p-major)
#define HW    (H_ * W_)    // 4096
#define NKT   72           // K-tiles of 32
#define PAD   66
#define PLANE (PAD * PAD)  // 4356 padded pixels per (b, cb4) plane

typedef __attribute__((ext_vector_type(8))) short short8;
typedef __attribute__((ext_vector_type(4))) float f32x4;
typedef unsigned short ushort_t;

static __device__ __forceinline__ ushort_t f2bf(float f) {
    __hip_bfloat16 h = __float2bfloat16(f);
    return *reinterpret_cast<ushort_t*>(&h);
}

typedef __attribute__((address_space(3))) unsigned int lds_u32;
typedef __attribute__((address_space(1))) const unsigned int glb_u32;
static __device__ __forceinline__ void gl_lds16(const ushort_t* g, ushort_t* l) {
    __builtin_amdgcn_global_load_lds((glb_u32*)g, (lds_u32*)l, 16, 0, 0);
}

#define BARRIER() asm volatile("s_barrier" ::: "memory")
#define VMCNTN(N) asm volatile("s_waitcnt vmcnt(" #N ")" ::: "memory")

// ---------------------------------------------------------------------------
// Kernel 1: rw[b][cout][p*256 + cin] (bf16, p-major), grid (256, B_).
// Fused rot: threads 0..3 compute this sample's 4 alpha-scaled 9x9 matrices.
// ---------------------------------------------------------------------------
__global__ __launch_bounds__(256)
void build_rw_kernel(const float* __restrict__ weight,
                     const float* __restrict__ alphas,
                     const float* __restrict__ angles,
                     ushort_t* __restrict__ rw) {
    __shared__ float rms[N_ * 81];        // 324 floats
    int tid = threadIdx.x;
    int b = blockIdx.y;

    if (tid < N_) {
        int i = b * N_ + tid;
        float th = angles[i], al = alphas[i];
        float xc = cosf(th), ys = sinf(th);
        float a = xc - ys, bb = xc * ys, c = xc + ys;
        float r[81];
#pragma unroll
        for (int j = 0; j < 81; ++j) r[j] = 0.f;
        if (th >= 0.f) {
            r[0] = a;          r[1] = 1.f - a;
            r[10] = xc - bb;   r[11] = bb;       r[13] = 1.f - c + bb; r[14] = ys - bb;
            r[20] = a;         r[23] = 1.f - a;
            r[27] = bb;        r[28] = ys - bb;  r[30] = xc - bb;      r[31] = 1.f - c + bb;
            r[40] = 1.f;
            r[49] = 1.f - c + bb; r[50] = xc - bb; r[52] = ys - bb;    r[53] = bb;
            r[57] = 1.f - a;   r[60] = a;
            r[66] = ys - bb;   r[67] = 1.f - c + bb; r[69] = bb;       r[70] = xc - bb;
            r[79] = 1.f - a;   r[80] = a;
        } else {
            r[0] = c;          r[3] = 1.f - c;
            r[9] = -bb;        r[10] = xc + bb;  r[12] = bb - ys;      r[13] = 1.f - a - bb;
            r[19] = 1.f - c;   r[20] = c;
            r[30] = xc + bb;   r[31] = 1.f - a - bb; r[33] = -bb;      r[34] = bb - ys;
            r[40] = 1.f;
            r[46] = bb - ys;   r[47] = -bb;      r[49] = 1.f - a - bb; r[50] = xc + bb;
            r[60] = c;         r[61] = 1.f - c;
            r[67] = 1.f - a - bb; r[68] = bb - ys; r[70] = xc + bb;    r[71] = -bb;
            r[77] = 1.f - c;   r[80] = c;
        }
#pragma unroll
        for (int j = 0; j < 81; ++j) rms[tid * 81 + j] = r[j] * al;
    }
    __syncthreads();

    int idx = blockIdx.x * 256 + tid;     // cout*256 + cin
    int cout = idx >> 8, cin = idx & 255;

    float wv[N_][9];
#pragma unroll
    for (int n = 0; n < N_; ++n)
#pragma unroll
        for (int q = 0; q < 9; ++q)
            wv[n][q] = weight[(size_t)(n * (COUT * CIN) + idx) * 9 + q];

    ushort_t* dst = rw + (size_t)(b * COUT + cout) * K_TOT + cin;
#pragma unroll
    for (int p = 0; p < 9; ++p) {
        float s = 0.f;
#pragma unroll
        for (int n = 0; n < N_; ++n)
#pragma unroll
            for (int q = 0; q < 9; ++q)
                s += rms[n * 81 + p * 9 + q] * wv[n][q];
        dst[p * 256] = f2bf(s);           // coalesced across cin lanes
    }
}

// ---------------------------------------------------------------------------
// Kernel 2 (fused nhwc repack + halo zero): x fp32 [b][c][64][64] -> xt bf16
//   [b][cb4(4)][y+1][x+1][64cin], plus zeroed halo ring.
// grid (64 rows, 8 cb32, B_), 256 thr.
// ---------------------------------------------------------------------------
__global__ __launch_bounds__(256)
void nhwc_kernel(const float* __restrict__ x, ushort_t* __restrict__ xt) {
    int y    = blockIdx.x;
    int cb32 = blockIdx.y;
    int b    = blockIdx.z;
    __shared__ ushort_t tileT[64][40];    // [px][ci(32)], 80B rows
    int t = threadIdx.x;

    ushort_t* plane = xt + (size_t)(b * 4 + (cb32 >> 1)) * PLANE * 64 + (cb32 & 1) * 32;
    const int4 z = {0, 0, 0, 0};

    int ci = t & 31, seg = t >> 5;        // 8 segs x 8 px
    const float* src = x + ((size_t)(b * CIN + cb32 * 32 + ci) * HW + y * 64 + seg * 8);
    float4 f0 = ((const float4*)src)[0];
    float4 f1 = ((const float4*)src)[1];
#pragma unroll
    for (int q = 0; q < 4; ++q) tileT[seg * 8 + q][ci]     = f2bf(((float*)&f0)[q]);
#pragma unroll
    for (int q = 0; q < 4; ++q) tileT[seg * 8 + 4 + q][ci] = f2bf(((float*)&f1)[q]);

    // ---- halo: left/right pad of this row (r = y+1), this 32-cin half ----
    if (t < 8) {
        int col = (t >> 2) ? 65 : 0;
        int sg  = t & 3;
        *(int4*)(plane + ((size_t)(y + 1) * PAD + col) * 64 + sg * 8) = z;
    }
    // ---- halo: top/bottom rows (y==0 blocks only) ----
    if (y == 0) {
        for (int u = t; u < 528; u += 256) {
            int row = (u >= 264) ? 65 : 0;
            int v = (u >= 264) ? u - 264 : u;   // 0..263
            int px = v >> 2, sg = v & 3;
            *(int4*)(plane + ((size_t)row * PAD + px) * 64 + sg * 8) = z;
        }
    }
    __syncthreads();

    int px = t >> 2, cseg = t & 3;        // 64 px x 4 x 16B
    ushort_t* dst = plane + ((size_t)(y + 1) * PAD + px + 1) * 64 + cseg * 8;
    *(int4*)dst = *(const int4*)&tileT[px][cseg * 8];
}

// ---------------------------------------------------------------------------
// Kernel 3: 256x256 implicit-GEMM conv (byte-identical to R14 best, 90-91us).
// BK=32, ring-3 LDS + cross-tile register fragment prefetch; pair-row 128B
// LDS rows + involution swizzle (0-conflict), setprio, XCD swizzle.
// 512 thr = 8 waves (2Mx4N), wave 128x64, acc[8][4].
// ---------------------------------------------------------------------------
__global__ __launch_bounds__(512, 1)
void conv_kernel(const ushort_t* __restrict__ xt,
                 const ushort_t* __restrict__ rw,
                 float* __restrict__ out) {
    int bid0 = blockIdx.x;
    int bid = (bid0 & 7) * 32 + (bid0 >> 3);   // 256 = 8*32: bijective
    int b     = bid >> 4;
    int ptile = bid & 15;       // pixel tile: 4 image rows
    int y0 = ptile * 4;
    int tid = threadIdx.x;
    int lane = tid & 63, wid = tid >> 6;
    int wm = wid >> 2, wn = wid & 3;
    int rA = lane & 15, kseg = lane >> 4;

    __shared__ __align__(16) ushort_t As[3][8192];   // 3 x 16 KB (256 rows x 32k)
    __shared__ __align__(16) ushort_t Bs[3][8192];   // 3 x 16 KB (256 px x 32k)
    ushort_t* AsB = &As[0][0];
    ushort_t* BsB = &Bs[0][0];

    f32x4 acc[8][4] = {};

    const ushort_t* rwb = rw + (size_t)b * COUT * K_TOT;
    const ushort_t* xtb = xt + ((size_t)b * 4 * PLANE + (size_t)y0 * PAD) * 64;

    // ---- staging geometry (pair-row packing, R12-proven) ----
    int asrc[2], bsrc[2], uDst[2];
#pragma unroll
    for (int i = 0; i < 2; ++i) {
        int u = i * 512 + tid;
        int l = u >> 3, s = u & 7;
        int c = s ^ (l & 7);
        int row = 2 * l + (c >> 2);                // 0..255
        asrc[i] = row * K_TOT + (c & 3) * 8;
        bsrc[i] = ((row >> 6) * PAD + (row & 63)) * 64 + (c & 3) * 8;
        uDst[i] = u * 8;
    }
    // ---- read geometry (lane-constant slot, R12-proven) ----
    const int slotR = (kseg + 4 * (rA & 1)) ^ ((rA >> 1) & 7);
    const int aRd = (wm * 64 + (rA >> 1)) * 64 + slotR * 8;   // + mi*512
    const int bRd = (wn * 32 + (rA >> 1)) * 64 + slotR * 8;   // + ni*512

#define STAGE_AB(KT, Q)                                                        \
    {                                                                          \
        int p_ = (KT) >> 3, sub_ = (KT) & 7;                                   \
        int ako = p_ * 256 + sub_ * 32;                                        \
        gl_lds16(rwb + asrc[0] + ako, AsB + (Q) * 8192 + uDst[0]);             \
        gl_lds16(rwb + asrc[1] + ako, AsB + (Q) * 8192 + uDst[1]);             \
        int ph_ = p_ / 3, pw_ = p_ - 3 * ph_;                                  \
        const ushort_t* sb_ = xtb + (size_t)((sub_ >> 1) * PLANE + ph_ * PAD + pw_) * 64 \
                              + (sub_ & 1) * 32;                               \
        gl_lds16(sb_ + bsrc[0], BsB + (Q) * 8192 + uDst[0]);                   \
        gl_lds16(sb_ + bsrc[1], BsB + (Q) * 8192 + uDst[1]);                   \
    }

#define READ_FRAGS(Q, AF, BF)                                                  \
    _Pragma("unroll")                                                          \
    for (int mi = 0; mi < 8; ++mi)                                             \
        AF[mi] = *(const short8*)(AsB + (Q) * 8192 + aRd + mi * 512);          \
    _Pragma("unroll")                                                          \
    for (int ni = 0; ni < 4; ++ni)                                             \
        BF[ni] = *(const short8*)(BsB + (Q) * 8192 + bRd + ni * 512);

    // body: prefetch frags(kt+1) into (AFN,BFN); stage kt+2; MFMA on (AFC,BFC)
#define TILE_BODY(KT, QN, QS, AFC, BFC, AFN, BFN)                              \
    {                                                                          \
        if ((KT) + 1 < NKT) { READ_FRAGS(QN, AFN, BFN); }                      \
        if ((KT) + 2 < NKT) { STAGE_AB((KT) + 2, QS); }                        \
        __builtin_amdgcn_s_setprio(1);                                         \
        _Pragma("unroll")                                                      \
        for (int mi = 0; mi < 8; ++mi)                                         \
            _Pragma("unroll")                                                  \
            for (int ni = 0; ni < 4; ++ni)                                     \
                acc[mi][ni] = __builtin_amdgcn_mfma_f32_16x16x32_bf16(         \
                    AFC[mi], BFC[ni], acc[mi][ni], 0, 0, 0);                   \
        __builtin_amdgcn_s_setprio(0);                                         \
        VMCNTN(0);                                                             \
        BARRIER();                                                             \
    }

    // ---- prologue: stage tiles 0,1 into buffers 0,1; prefetch frags(0) ----
    STAGE_AB(0, 0);
    STAGE_AB(1, 1);
    VMCNTN(0);
    BARRIER();

    short8 afA[8], bfA[4], afB[8], bfB[4];
    READ_FRAGS(0, afA, bfA);

    int qc = 0;                      // buffer of current tile
    for (int kt = 0; kt < NKT; kt += 2) {
        int qn = qc + 1; if (qn >= 3) qn -= 3;
        int qs = qc + 2; if (qs >= 3) qs -= 3;
        TILE_BODY(kt, qn, qs, afA, bfA, afB, bfB);
        // second tile of pair: current buffer qn
        int qn2 = qs;
        int qs2 = qc;
        TILE_BODY(kt + 1, qn2, qs2, afB, bfB, afA, bfA);
        qc = qs;                     // (qc+2)%3 after two tiles
    }
#undef TILE_BODY
#undef READ_FRAGS
#undef STAGE_AB

    // ---- epilogue: D[row=(lane>>4)*4+rr][col=lane&15] ----
    int row0 = (lane >> 4) * 4;
    int col  = lane & 15;
    float* outb = out + (size_t)b * COUT * HW + ptile * 256;
#pragma unroll
    for (int am = 0; am < 8; ++am)
#pragma unroll
        for (int an = 0; an < 4; ++an)
#pragma unroll
            for (int rr = 0; rr < 4; ++rr) {
                int m = wm * 128 + am * 16 + row0 + rr;
                int n = wn * 64 + an * 16 + col;
                outb[(size_t)m * HW + n] = acc[am][an][rr];
            }
}

// ---------------------------------------------------------------------------
extern "C" void kernel_launch(void* const* d_in, const int* in_sizes, int n_in,
                              void* d_out, int out_size, void* d_ws, size_t ws_size,
                              hipStream_t stream) {
    const float* x      = (const float*)d_in[0];
    const float* alphas = (const float*)d_in[1];
    const float* angles = (const float*)d_in[2];
    const float* weight = (const float*)d_in[3];
    float* out = (float*)d_out;

    // ws: rw 18.87 MB | xt 35.68 MB
    ushort_t* rw = (ushort_t*)d_ws;
    ushort_t* xt = (ushort_t*)((char*)d_ws + (size_t)B_ * COUT * K_TOT * 2);

    build_rw_kernel<<<dim3(COUT * CIN / 256, B_), 256, 0, stream>>>(weight, alphas, angles, rw);
    nhwc_kernel<<<dim3(64, 8, B_), 256, 0, stream>>>(x, xt);
    conv_kernel<<<256, 512, 0, stream>>>(xt, rw, out);
}

// Round 17
// 107.376 us; speedup vs baseline: 1.1847x; 1.0387x over previous
//
#include <hip/hip_runtime.h>
#include <hip/hip_bf16.h>

#define B_    16
#define N_    4
#define COUT  256
#define CIN   256
#define H_    64
#define W_    64
#define K_TOT (CIN * 9)    // 2304, k = p*256 + cin (p-major)
#define HW    (H_ * W_)    // 4096
#define NKT   36           // K-tiles of 64
#define PAD   66
#define PLANE (PAD * PAD)  // 4356 padded pixels per (b, cb4) plane

typedef __attribute__((ext_vector_type(8))) short short8;
typedef __attribute__((ext_vector_type(4))) float f32x4;
typedef unsigned short ushort_t;

static __device__ __forceinline__ ushort_t f2bf(float f) {
    __hip_bfloat16 h = __float2bfloat16(f);
    return *reinterpret_cast<ushort_t*>(&h);
}

typedef __attribute__((address_space(3))) unsigned int lds_u32;
typedef __attribute__((address_space(1))) const unsigned int glb_u32;
static __device__ __forceinline__ void gl_lds16(const ushort_t* g, ushort_t* l) {
    __builtin_amdgcn_global_load_lds((glb_u32*)g, (lds_u32*)l, 16, 0, 0);
}

#define BARRIER() asm volatile("s_barrier" ::: "memory")
#define VMCNTN(N) asm volatile("s_waitcnt vmcnt(" #N ")" ::: "memory")

// ---------------------------------------------------------------------------
// Kernel 1: rw[b][cout][p*256 + cin] (bf16, p-major), grid (256, B_).
// Fused rot: threads 0..3 compute this sample's 4 alpha-scaled 9x9 matrices.
// ---------------------------------------------------------------------------
__global__ __launch_bounds__(256)
void build_rw_kernel(const float* __restrict__ weight,
                     const float* __restrict__ alphas,
                     const float* __restrict__ angles,
                     ushort_t* __restrict__ rw) {
    __shared__ float rms[N_ * 81];        // 324 floats
    int tid = threadIdx.x;
    int b = blockIdx.y;

    if (tid < N_) {
        int i = b * N_ + tid;
        float th = angles[i], al = alphas[i];
        float xc = cosf(th), ys = sinf(th);
        float a = xc - ys, bb = xc * ys, c = xc + ys;
        float r[81];
#pragma unroll
        for (int j = 0; j < 81; ++j) r[j] = 0.f;
        if (th >= 0.f) {
            r[0] = a;          r[1] = 1.f - a;
            r[10] = xc - bb;   r[11] = bb;       r[13] = 1.f - c + bb; r[14] = ys - bb;
            r[20] = a;         r[23] = 1.f - a;
            r[27] = bb;        r[28] = ys - bb;  r[30] = xc - bb;      r[31] = 1.f - c + bb;
            r[40] = 1.f;
            r[49] = 1.f - c + bb; r[50] = xc - bb; r[52] = ys - bb;    r[53] = bb;
            r[57] = 1.f - a;   r[60] = a;
            r[66] = ys - bb;   r[67] = 1.f - c + bb; r[69] = bb;       r[70] = xc - bb;
            r[79] = 1.f - a;   r[80] = a;
        } else {
            r[0] = c;          r[3] = 1.f - c;
            r[9] = -bb;        r[10] = xc + bb;  r[12] = bb - ys;      r[13] = 1.f - a - bb;
            r[19] = 1.f - c;   r[20] = c;
            r[30] = xc + bb;   r[31] = 1.f - a - bb; r[33] = -bb;      r[34] = bb - ys;
            r[40] = 1.f;
            r[46] = bb - ys;   r[47] = -bb;      r[49] = 1.f - a - bb; r[50] = xc + bb;
            r[60] = c;         r[61] = 1.f - c;
            r[67] = 1.f - a - bb; r[68] = bb - ys; r[70] = xc + bb;    r[71] = -bb;
            r[77] = 1.f - c;   r[80] = c;
        }
#pragma unroll
        for (int j = 0; j < 81; ++j) rms[tid * 81 + j] = r[j] * al;
    }
    __syncthreads();

    int idx = blockIdx.x * 256 + tid;     // cout*256 + cin
    int cout = idx >> 8, cin = idx & 255;

    float wv[N_][9];
#pragma unroll
    for (int n = 0; n < N_; ++n)
#pragma unroll
        for (int q = 0; q < 9; ++q)
            wv[n][q] = weight[(size_t)(n * (COUT * CIN) + idx) * 9 + q];

    ushort_t* dst = rw + (size_t)(b * COUT + cout) * K_TOT + cin;
#pragma unroll
    for (int p = 0; p < 9; ++p) {
        float s = 0.f;
#pragma unroll
        for (int n = 0; n < N_; ++n)
#pragma unroll
            for (int q = 0; q < 9; ++q)
                s += rms[n * 81 + p * 9 + q] * wv[n][q];
        dst[p * 256] = f2bf(s);           // coalesced across cin lanes
    }
}

// ---------------------------------------------------------------------------
// Kernel 2 (fused nhwc repack + halo zero): x fp32 [b][c][64][64] -> xt bf16
//   [b][cb4(4)][y+1][x+1][64cin], plus zeroed halo ring.
// grid (64 rows, 8 cb32, B_), 256 thr.
// ---------------------------------------------------------------------------
__global__ __launch_bounds__(256)
void nhwc_kernel(const float* __restrict__ x, ushort_t* __restrict__ xt) {
    int y    = blockIdx.x;
    int cb32 = blockIdx.y;
    int b    = blockIdx.z;
    __shared__ ushort_t tileT[64][40];    // [px][ci(32)], 80B rows
    int t = threadIdx.x;

    ushort_t* plane = xt + (size_t)(b * 4 + (cb32 >> 1)) * PLANE * 64 + (cb32 & 1) * 32;
    const int4 z = {0, 0, 0, 0};

    int ci = t & 31, seg = t >> 5;        // 8 segs x 8 px
    const float* src = x + ((size_t)(b * CIN + cb32 * 32 + ci) * HW + y * 64 + seg * 8);
    float4 f0 = ((const float4*)src)[0];
    float4 f1 = ((const float4*)src)[1];
#pragma unroll
    for (int q = 0; q < 4; ++q) tileT[seg * 8 + q][ci]     = f2bf(((float*)&f0)[q]);
#pragma unroll
    for (int q = 0; q < 4; ++q) tileT[seg * 8 + 4 + q][ci] = f2bf(((float*)&f1)[q]);

    // ---- halo: left/right pad of this row (r = y+1), this 32-cin half ----
    if (t < 8) {
        int col = (t >> 2) ? 65 : 0;
        int sg  = t & 3;
        *(int4*)(plane + ((size_t)(y + 1) * PAD + col) * 64 + sg * 8) = z;
    }
    // ---- halo: top/bottom rows (y==0 blocks only) ----
    if (y == 0) {
        for (int u = t; u < 528; u += 256) {
            int row = (u >= 264) ? 65 : 0;
            int v = (u >= 264) ? u - 264 : u;   // 0..263
            int px = v >> 2, sg = v & 3;
            *(int4*)(plane + ((size_t)row * PAD + px) * 64 + sg * 8) = z;
        }
    }
    __syncthreads();

    int px = t >> 2, cseg = t & 3;        // 64 px x 4 x 16B
    ushort_t* dst = plane + ((size_t)(y + 1) * PAD + px + 1) * 64 + cseg * 8;
    *(int4*)dst = *(const int4*)&tileT[px][cseg * 8];
}

// ---------------------------------------------------------------------------
// Kernel 3: 256x256 implicit-GEMM conv, BK=64, dbuf LDS, 4 phases/K-tile
// (R8 structure) + COUNTED vmcnt(2) via quarter-mapped staging (T4 proper).
// Stage order per tile (of kt+1): ph1 B-q01, ph2 B-q23, ph3 A-q{0,2}(mh0),
// ph4 A-q{1,3}(mh1). Waits: vmcnt(2) end-ph4 (publishes B+A-mh0) and
// vmcnt(2) end-ph1 (publishes A-mh1). Loads never drained to 0 mid-loop.
// 512 thr = 8 waves (2M x 4N), wave 128x64, acc[8][4]; swizzle ^(rA&7)
// both sides (0-conflict, R8-proven); setprio; bijective XCD swizzle.
// LDS = 2 x (32KB A + 32KB B) = 128 KB, grid 256 = one residency pass.
// ---------------------------------------------------------------------------
__global__ __launch_bounds__(512, 1)
void conv_kernel(const ushort_t* __restrict__ xt,
                 const ushort_t* __restrict__ rw,
                 float* __restrict__ out) {
    int bid0 = blockIdx.x;
    int bid = (bid0 & 7) * 32 + (bid0 >> 3);   // 256 = 8*32: bijective
    int b     = bid >> 4;
    int ptile = bid & 15;       // pixel tile: 4 image rows
    int y0 = ptile * 4;
    int tid = threadIdx.x;
    int lane = tid & 63, wid = tid >> 6;
    int wm = wid >> 2, wn = wid & 3;
    int rA = lane & 15, kseg = lane >> 4;

    __shared__ __align__(16) ushort_t As[2][16384];   // 2 x 32 KB (256 rows x 64k)
    __shared__ __align__(16) ushort_t Bs[2][16384];   // 2 x 32 KB (256 px x 64k)
    ushort_t* AsB = &As[0][0];
    ushort_t* BsB = &Bs[0][0];

    f32x4 acc[8][4] = {};

    const ushort_t* rwb = rw + (size_t)b * COUT * K_TOT;
    const ushort_t* xtb = xt + ((size_t)b * 4 * PLANE + (size_t)y0 * PAD) * 64;

    // ---- quarter-mapped staging: unit u = q*512 + tid (16B each) ----
    // row/px = q*64 + (tid>>3); dest chunk = tid&7; src chunk = dst ^ (row&7)
    const int rq = tid >> 3;                        // 0..63 row-in-quarter
    const int cs = ((tid & 7) ^ (rq & 7)) * 8;      // src chunk offset (elems)
    const int dl = tid * 8;                         // dest offset within quarter

    // read-side swizzled slot (lane-constant): ((KH*4+kseg) ^ (rA&7)) * 8
#define RSLOT(KH) ((((KH) << 2) | kseg) ^ (rA & 7)) * 8

#define STAGE_A2(KT, Q, Q0, Q1)                                                \
    {                                                                          \
        int p_ = (KT) >> 2, c4_ = (KT) & 3;                                    \
        int ako = p_ * 256 + c4_ * 64;                                         \
        gl_lds16(rwb + (size_t)((Q0) * 64 + rq) * K_TOT + cs + ako,            \
                 AsB + (Q) * 16384 + (Q0) * 4096 + dl);                        \
        gl_lds16(rwb + (size_t)((Q1) * 64 + rq) * K_TOT + cs + ako,            \
                 AsB + (Q) * 16384 + (Q1) * 4096 + dl);                        \
    }

#define STAGE_B2(KT, Q, Q0, Q1)                                                \
    {                                                                          \
        int p_ = (KT) >> 2, c4_ = (KT) & 3;                                    \
        int ph_ = p_ / 3, pw_ = p_ - 3 * ph_;                                  \
        const ushort_t* sb_ = xtb + (size_t)(c4_ * PLANE + ph_ * PAD + pw_) * 64; \
        gl_lds16(sb_ + (size_t)((Q0) * PAD + rq) * 64 + cs,                    \
                 BsB + (Q) * 16384 + (Q0) * 4096 + dl);                        \
        gl_lds16(sb_ + (size_t)((Q1) * PAD + rq) * 64 + cs,                    \
                 BsB + (Q) * 16384 + (Q1) * 4096 + dl);                        \
    }

#define READ_AF(Q, MH, KH)                                                     \
    _Pragma("unroll")                                                          \
    for (int mi = 0; mi < 4; ++mi) {                                           \
        int row = wm * 128 + (MH) * 64 + mi * 16 + rA;                         \
        af[mi] = *(const short8*)(AsB + (Q) * 16384 + row * 64 + RSLOT(KH));   \
    }

#define READ_BF(Q, KH)                                                         \
    _Pragma("unroll")                                                          \
    for (int ni = 0; ni < 4; ++ni) {                                           \
        int row = wn * 64 + ni * 16 + rA;                                      \
        bf[ni] = *(const short8*)(BsB + (Q) * 16384 + row * 64 + RSLOT(KH));   \
    }

#define DO_MFMA(MH)                                                            \
    __builtin_amdgcn_s_setprio(1);                                             \
    _Pragma("unroll")                                                          \
    for (int mi = 0; mi < 4; ++mi)                                             \
        _Pragma("unroll")                                                      \
        for (int ni = 0; ni < 4; ++ni)                                         \
            acc[(MH) * 4 + mi][ni] = __builtin_amdgcn_mfma_f32_16x16x32_bf16(  \
                af[mi], bf[ni], acc[(MH) * 4 + mi][ni], 0, 0, 0);              \
    __builtin_amdgcn_s_setprio(0);

    // ---- prologue: tile 0 into buffer 0 (order B01,B23,A02,A13) ----
    STAGE_B2(0, 0, 0, 1);
    STAGE_B2(0, 0, 2, 3);
    STAGE_A2(0, 0, 0, 2);     // mh0 rows (quarters 0,2)
    STAGE_A2(0, 0, 1, 3);     // mh1 rows (quarters 1,3)
    VMCNTN(2);                // B + A-mh0 landed; A-mh1 pair in flight
    BARRIER();

    short8 af[4], bf[4];
    for (int kt = 0; kt < NKT; ++kt) {
        int q = kt & 1, qn = q ^ 1;
        bool more = (kt + 1 < NKT);
        // ---- phase 1: mh0/kh0; stage B-q01 of kt+1 ----
        READ_AF(q, 0, 0);
        READ_BF(q, 0);
        if (more) STAGE_B2(kt + 1, qn, 0, 1);
        BARRIER();
        DO_MFMA(0);
        if (more) { VMCNTN(2); } else { VMCNTN(0); }   // publish A-mh1(kt)
        BARRIER();
        // ---- phase 2: mh1/kh0; stage B-q23 of kt+1 ----
        READ_AF(q, 1, 0);
        if (more) STAGE_B2(kt + 1, qn, 2, 3);
        BARRIER();
        DO_MFMA(1);
        BARRIER();
        // ---- phase 3: mh0/kh1; stage A-mh0 of kt+1 ----
        READ_AF(q, 0, 1);
        READ_BF(q, 1);
        if (more) STAGE_A2(kt + 1, qn, 0, 2);
        BARRIER();
        DO_MFMA(0);
        BARRIER();
        // ---- phase 4: mh1/kh1; stage A-mh1 of kt+1 ----
        READ_AF(q, 1, 1);
        if (more) STAGE_A2(kt + 1, qn, 1, 3);
        BARRIER();
        DO_MFMA(1);
        VMCNTN(2);            // publish B + A-mh0 of kt+1 (A-mh1 in flight)
        BARRIER();
    }
#undef STAGE_A2
#undef STAGE_B2
#undef READ_AF
#undef READ_BF
#undef DO_MFMA
#undef RSLOT

    // ---- epilogue: D[row=(lane>>4)*4+rr][col=lane&15] ----
    int row0 = (lane >> 4) * 4;
    int col  = lane & 15;
    float* outb = out + (size_t)b * COUT * HW + ptile * 256;
#pragma unroll
    for (int am = 0; am < 8; ++am)
#pragma unroll
        for (int an = 0; an < 4; ++an)
#pragma unroll
            for (int rr = 0; rr < 4; ++rr) {
                int m = wm * 128 + am * 16 + row0 + rr;
                int n = wn * 64 + an * 16 + col;
                outb[(size_t)m * HW + n] = acc[am][an][rr];
            }
}

// ---------------------------------------------------------------------------
extern "C" void kernel_launch(void* const* d_in, const int* in_sizes, int n_in,
                              void* d_out, int out_size, void* d_ws, size_t ws_size,
                              hipStream_t stream) {
    const float* x      = (const float*)d_in[0];
    const float* alphas = (const float*)d_in[1];
    const float* angles = (const float*)d_in[2];
    const float* weight = (const float*)d_in[3];
    float* out = (float*)d_out;

    // ws: rw 18.87 MB | xt 35.68 MB
    ushort_t* rw = (ushort_t*)d_ws;
    ushort_t* xt = (ushort_t*)((char*)d_ws + (size_t)B_ * COUT * K_TOT * 2);

    build_rw_kernel<<<dim3(COUT * CIN / 256, B_), 256, 0, stream>>>(weight, alphas, angles, rw);
    nhwc_kernel<<<dim3(64, 8, B_), 256, 0, stream>>>(x, xt);
    conv_kernel<<<256, 512, 0, stream>>>(xt, rw, out);
}

// Round 18
// 107.227 us; speedup vs baseline: 1.1863x; 1.0014x over previous
//
#include <hip/hip_runtime.h>
#include <hip/hip_bf16.h>

#define B_    16
#define N_    4
#define COUT  256
#define CIN   256
#define H_    64
#define W_    64
#define K_TOT (CIN * 9)    // 2304, k = p*256 + cin (p-major)
#define HW    (H_ * W_)    // 4096
#define NKT   36           // K-tiles of 64
#define PAD   66
#define PLANE (PAD * PAD)  // 4356 padded pixels per (b, cb4) plane

typedef __attribute__((ext_vector_type(8))) short short8;
typedef __attribute__((ext_vector_type(4))) float f32x4;
typedef unsigned short ushort_t;

static __device__ __forceinline__ ushort_t f2bf(float f) {
    __hip_bfloat16 h = __float2bfloat16(f);
    return *reinterpret_cast<ushort_t*>(&h);
}

typedef __attribute__((address_space(3))) unsigned int lds_u32;
typedef __attribute__((address_space(1))) const unsigned int glb_u32;
static __device__ __forceinline__ void gl_lds16(const ushort_t* g, ushort_t* l) {
    __builtin_amdgcn_global_load_lds((glb_u32*)g, (lds_u32*)l, 16, 0, 0);
}

#define BARRIER() asm volatile("s_barrier" ::: "memory")
#define VMCNTN(N) asm volatile("s_waitcnt vmcnt(" #N ")" ::: "memory")

// ---------------------------------------------------------------------------
// Kernel 1: rw[b][cout][p*256 + cin] (bf16, p-major), grid (256, B_).
// Fused rot: threads 0..3 compute this sample's 4 alpha-scaled 9x9 matrices.
// ---------------------------------------------------------------------------
__global__ __launch_bounds__(256)
void build_rw_kernel(const float* __restrict__ weight,
                     const float* __restrict__ alphas,
                     const float* __restrict__ angles,
                     ushort_t* __restrict__ rw) {
    __shared__ float rms[N_ * 81];        // 324 floats
    int tid = threadIdx.x;
    int b = blockIdx.y;

    if (tid < N_) {
        int i = b * N_ + tid;
        float th = angles[i], al = alphas[i];
        float xc = cosf(th), ys = sinf(th);
        float a = xc - ys, bb = xc * ys, c = xc + ys;
        float r[81];
#pragma unroll
        for (int j = 0; j < 81; ++j) r[j] = 0.f;
        if (th >= 0.f) {
            r[0] = a;          r[1] = 1.f - a;
            r[10] = xc - bb;   r[11] = bb;       r[13] = 1.f - c + bb; r[14] = ys - bb;
            r[20] = a;         r[23] = 1.f - a;
            r[27] = bb;        r[28] = ys - bb;  r[30] = xc - bb;      r[31] = 1.f - c + bb;
            r[40] = 1.f;
            r[49] = 1.f - c + bb; r[50] = xc - bb; r[52] = ys - bb;    r[53] = bb;
            r[57] = 1.f - a;   r[60] = a;
            r[66] = ys - bb;   r[67] = 1.f - c + bb; r[69] = bb;       r[70] = xc - bb;
            r[79] = 1.f - a;   r[80] = a;
        } else {
            r[0] = c;          r[3] = 1.f - c;
            r[9] = -bb;        r[10] = xc + bb;  r[12] = bb - ys;      r[13] = 1.f - a - bb;
            r[19] = 1.f - c;   r[20] = c;
            r[30] = xc + bb;   r[31] = 1.f - a - bb; r[33] = -bb;      r[34] = bb - ys;
            r[40] = 1.f;
            r[46] = bb - ys;   r[47] = -bb;      r[49] = 1.f - a - bb; r[50] = xc + bb;
            r[60] = c;         r[61] = 1.f - c;
            r[67] = 1.f - a - bb; r[68] = bb - ys; r[70] = xc + bb;    r[71] = -bb;
            r[77] = 1.f - c;   r[80] = c;
        }
#pragma unroll
        for (int j = 0; j < 81; ++j) rms[tid * 81 + j] = r[j] * al;
    }
    __syncthreads();

    int idx = blockIdx.x * 256 + tid;     // cout*256 + cin
    int cout = idx >> 8, cin = idx & 255;

    float wv[N_][9];
#pragma unroll
    for (int n = 0; n < N_; ++n)
#pragma unroll
        for (int q = 0; q < 9; ++q)
            wv[n][q] = weight[(size_t)(n * (COUT * CIN) + idx) * 9 + q];

    ushort_t* dst = rw + (size_t)(b * COUT + cout) * K_TOT + cin;
#pragma unroll
    for (int p = 0; p < 9; ++p) {
        float s = 0.f;
#pragma unroll
        for (int n = 0; n < N_; ++n)
#pragma unroll
            for (int q = 0; q < 9; ++q)
                s += rms[n * 81 + p * 9 + q] * wv[n][q];
        dst[p * 256] = f2bf(s);           // coalesced across cin lanes
    }
}

// ---------------------------------------------------------------------------
// Kernel 2 (fused nhwc repack + halo zero): x fp32 [b][c][64][64] -> xt bf16
//   [b][cb4(4)][y+1][x+1][64cin], plus zeroed halo ring.
// grid (64 rows, 8 cb32, B_), 256 thr.
// ---------------------------------------------------------------------------
__global__ __launch_bounds__(256)
void nhwc_kernel(const float* __restrict__ x, ushort_t* __restrict__ xt) {
    int y    = blockIdx.x;
    int cb32 = blockIdx.y;
    int b    = blockIdx.z;
    __shared__ ushort_t tileT[64][40];    // [px][ci(32)], 80B rows
    int t = threadIdx.x;

    ushort_t* plane = xt + (size_t)(b * 4 + (cb32 >> 1)) * PLANE * 64 + (cb32 & 1) * 32;
    const int4 z = {0, 0, 0, 0};

    int ci = t & 31, seg = t >> 5;        // 8 segs x 8 px
    const float* src = x + ((size_t)(b * CIN + cb32 * 32 + ci) * HW + y * 64 + seg * 8);
    float4 f0 = ((const float4*)src)[0];
    float4 f1 = ((const float4*)src)[1];
#pragma unroll
    for (int q = 0; q < 4; ++q) tileT[seg * 8 + q][ci]     = f2bf(((float*)&f0)[q]);
#pragma unroll
    for (int q = 0; q < 4; ++q) tileT[seg * 8 + 4 + q][ci] = f2bf(((float*)&f1)[q]);

    // ---- halo: left/right pad of this row (r = y+1), this 32-cin half ----
    if (t < 8) {
        int col = (t >> 2) ? 65 : 0;
        int sg  = t & 3;
        *(int4*)(plane + ((size_t)(y + 1) * PAD + col) * 64 + sg * 8) = z;
    }
    // ---- halo: top/bottom rows (y==0 blocks only) ----
    if (y == 0) {
        for (int u = t; u < 528; u += 256) {
            int row = (u >= 264) ? 65 : 0;
            int v = (u >= 264) ? u - 264 : u;   // 0..263
            int px = v >> 2, sg = v & 3;
            *(int4*)(plane + ((size_t)row * PAD + px) * 64 + sg * 8) = z;
        }
    }
    __syncthreads();

    int px = t >> 2, cseg = t & 3;        // 64 px x 4 x 16B
    ushort_t* dst = plane + ((size_t)(y + 1) * PAD + px + 1) * 64 + cseg * 8;
    *(int4*)dst = *(const int4*)&tileT[px][cseg * 8];
}

// ---------------------------------------------------------------------------
// Kernel 3: 256x256 implicit-GEMM conv, BK=64, 4 phases/K-tile with
// ASYMMETRIC pipeline depth: A dbuf staged 1 tile ahead (ph1-2, L2-resident
// rw), B ring-3 staged 2 tiles ahead (ph3-4, HBM-latency-prone xt) -> B
// issue-to-wait distance = 6 phases >> 900cy HBM latency. A issued BEFORE B
// within each tile so vmcnt (oldest-first) waits for A never drain B.
// Waits: vmcnt(6) end-ph1 (A-mh1 of kt) and end-ph4 (A-mh0 of kt+1; B(kt+1)
// is older, covered). Quarter-mapped staging, swizzle ^(rA&7) both sides
// (0-conflict), setprio, bijective XCD swizzle. 512 thr = 8 waves (2Mx4N),
// wave 128x64, acc[8][4]. LDS = 2x32KB A + 3x32KB B = 160 KB.
// ---------------------------------------------------------------------------
__global__ __launch_bounds__(512, 1)
void conv_kernel(const ushort_t* __restrict__ xt,
                 const ushort_t* __restrict__ rw,
                 float* __restrict__ out) {
    int bid0 = blockIdx.x;
    int bid = (bid0 & 7) * 32 + (bid0 >> 3);   // 256 = 8*32: bijective
    int b     = bid >> 4;
    int ptile = bid & 15;       // pixel tile: 4 image rows
    int y0 = ptile * 4;
    int tid = threadIdx.x;
    int lane = tid & 63, wid = tid >> 6;
    int wm = wid >> 2, wn = wid & 3;
    int rA = lane & 15, kseg = lane >> 4;

    __shared__ __align__(16) ushort_t As[2][16384];   // 2 x 32 KB
    __shared__ __align__(16) ushort_t Bs[3][16384];   // 3 x 32 KB
    ushort_t* AsB = &As[0][0];
    ushort_t* BsB = &Bs[0][0];

    f32x4 acc[8][4] = {};

    const ushort_t* rwb = rw + (size_t)b * COUT * K_TOT;
    const ushort_t* xtb = xt + ((size_t)b * 4 * PLANE + (size_t)y0 * PAD) * 64;

    // ---- quarter-mapped staging: unit u = q*512 + tid (16B each) ----
    const int rq = tid >> 3;                        // 0..63 row-in-quarter
    const int cs = ((tid & 7) ^ (rq & 7)) * 8;      // src chunk (pre-swizzled)
    const int dl = tid * 8;                         // dest offset in quarter

#define RSLOT(KH) ((((KH) << 2) | kseg) ^ (rA & 7)) * 8

#define STAGE_A2(KT, BUFO, Q0, Q1)                                             \
    {                                                                          \
        int p_ = (KT) >> 2, c4_ = (KT) & 3;                                    \
        int ako = p_ * 256 + c4_ * 64;                                         \
        gl_lds16(rwb + (size_t)((Q0) * 64 + rq) * K_TOT + cs + ako,            \
                 AsB + (BUFO) + (Q0) * 4096 + dl);                             \
        gl_lds16(rwb + (size_t)((Q1) * 64 + rq) * K_TOT + cs + ako,            \
                 AsB + (BUFO) + (Q1) * 4096 + dl);                             \
    }

#define STAGE_B2(KT, BUFO, Q0, Q1)                                             \
    {                                                                          \
        int p_ = (KT) >> 2, c4_ = (KT) & 3;                                    \
        int ph_ = p_ / 3, pw_ = p_ - 3 * ph_;                                  \
        const ushort_t* sb_ = xtb + (size_t)(c4_ * PLANE + ph_ * PAD + pw_) * 64; \
        gl_lds16(sb_ + (size_t)((Q0) * PAD + rq) * 64 + cs,                    \
                 BsB + (BUFO) + (Q0) * 4096 + dl);                             \
        gl_lds16(sb_ + (size_t)((Q1) * PAD + rq) * 64 + cs,                    \
                 BsB + (BUFO) + (Q1) * 4096 + dl);                             \
    }

#define READ_AF(BUFO, MH, KH)                                                  \
    _Pragma("unroll")                                                          \
    for (int mi = 0; mi < 4; ++mi) {                                           \
        int row = wm * 128 + (MH) * 64 + mi * 16 + rA;                         \
        af[mi] = *(const short8*)(AsB + (BUFO) + row * 64 + RSLOT(KH));        \
    }

#define READ_BF(BUFO, KH)                                                      \
    _Pragma("unroll")                                                          \
    for (int ni = 0; ni < 4; ++ni) {                                           \
        int row = wn * 64 + ni * 16 + rA;                                      \
        bf[ni] = *(const short8*)(BsB + (BUFO) + row * 64 + RSLOT(KH));        \
    }

#define DO_MFMA(MH)                                                            \
    __builtin_amdgcn_s_setprio(1);                                             \
    _Pragma("unroll")                                                          \
    for (int mi = 0; mi < 4; ++mi)                                             \
        _Pragma("unroll")                                                      \
        for (int ni = 0; ni < 4; ++ni)                                         \
            acc[(MH) * 4 + mi][ni] = __builtin_amdgcn_mfma_f32_16x16x32_bf16(  \
                af[mi], bf[ni], acc[(MH) * 4 + mi][ni], 0, 0, 0);              \
    __builtin_amdgcn_s_setprio(0);

    // ---- prologue: B(0), A(0), B(1); wait through A(0)-mh0 ----
    STAGE_B2(0, 0, 0, 1);
    STAGE_B2(0, 0, 2, 3);
    STAGE_A2(0, 0, 0, 2);
    STAGE_A2(0, 0, 1, 3);
    STAGE_B2(1, 16384, 0, 1);
    STAGE_B2(1, 16384, 2, 3);
    VMCNTN(6);            // B(0)+A(0)-mh0 landed; A(0)-mh1 + B(1) in flight
    BARRIER();

    short8 af[4], bf[4];
    int bq = 0;                       // B ring buffer of tile kt
    for (int kt = 0; kt < NKT; ++kt) {
        int bsq = bq + 2; if (bsq >= 3) bsq -= 3;
        const int abuf  = (kt & 1) << 14;
        const int anbuf = ((kt + 1) & 1) << 14;
        const int bbuf  = bq * 16384;
        const int bsbuf = bsq * 16384;
        bool moreA = (kt + 1 < NKT), moreB = (kt + 2 < NKT);

        // ---- phase 1: mh0/kh0; stage A(kt+1) q02 ----
        READ_AF(abuf, 0, 0);
        READ_BF(bbuf, 0);
        if (moreA) STAGE_A2(kt + 1, anbuf, 0, 2);
        BARRIER();
        DO_MFMA(0);
        if (moreA) { VMCNTN(6); } else { VMCNTN(0); }   // publish A(kt)-mh1
        BARRIER();
        // ---- phase 2: mh1/kh0; stage A(kt+1) q13 ----
        READ_AF(abuf, 1, 0);
        if (moreA) STAGE_A2(kt + 1, anbuf, 1, 3);
        BARRIER();
        DO_MFMA(1);
        BARRIER();
        // ---- phase 3: mh0/kh1; stage B(kt+2) q01 ----
        READ_AF(abuf, 0, 1);
        READ_BF(bbuf, 1);
        if (moreB) STAGE_B2(kt + 2, bsbuf, 0, 1);
        BARRIER();
        DO_MFMA(0);
        BARRIER();
        // ---- phase 4: mh1/kh1; stage B(kt+2) q23 ----
        READ_AF(abuf, 1, 1);
        if (moreB) STAGE_B2(kt + 2, bsbuf, 2, 3);
        BARRIER();
        DO_MFMA(1);
        if (moreB)      { VMCNTN(6); }  // publish A(kt+1)-mh0 (B(kt+1) older)
        else if (moreA) { VMCNTN(2); }
        else            { VMCNTN(0); }
        BARRIER();
        bq = (bq == 2) ? 0 : bq + 1;
    }
#undef STAGE_A2
#undef STAGE_B2
#undef READ_AF
#undef READ_BF
#undef DO_MFMA
#undef RSLOT

    // ---- epilogue: D[row=(lane>>4)*4+rr][col=lane&15] ----
    int row0 = (lane >> 4) * 4;
    int col  = lane & 15;
    float* outb = out + (size_t)b * COUT * HW + ptile * 256;
#pragma unroll
    for (int am = 0; am < 8; ++am)
#pragma unroll
        for (int an = 0; an < 4; ++an)
#pragma unroll
            for (int rr = 0; rr < 4; ++rr) {
                int m = wm * 128 + am * 16 + row0 + rr;
                int n = wn * 64 + an * 16 + col;
                outb[(size_t)m * HW + n] = acc[am][an][rr];
            }
}

// ---------------------------------------------------------------------------
extern "C" void kernel_launch(void* const* d_in, const int* in_sizes, int n_in,
                              void* d_out, int out_size, void* d_ws, size_t ws_size,
                              hipStream_t stream) {
    const float* x      = (const float*)d_in[0];
    const float* alphas = (const float*)d_in[1];
    const float* angles = (const float*)d_in[2];
    const float* weight = (const float*)d_in[3];
    float* out = (float*)d_out;

    // ws: rw 18.87 MB | xt 35.68 MB
    ushort_t* rw = (ushort_t*)d_ws;
    ushort_t* xt = (ushort_t*)((char*)d_ws + (size_t)B_ * COUT * K_TOT * 2);

    build_rw_kernel<<<dim3(COUT * CIN / 256, B_), 256, 0, stream>>>(weight, alphas, angles, rw);
    nhwc_kernel<<<dim3(64, 8, B_), 256, 0, stream>>>(x, xt);
    conv_kernel<<<256, 512, 0, stream>>>(xt, rw, out);
}